// Round 1
// baseline (5532.359 us; speedup 1.0000x reference)
//
#include <hip/hip_runtime.h>

// AdaptiveGraphConvolution on MI355X (gfx950)
// out = sum_l m_l * (A_l @ x) @ W_l + bias
//   (SpMM first on raw x -- best gather locality; GEMM folds mixing weights)
//
// Round 1 baseline: atomic scatter SpMM + LDS-tiled f32 GEMM-accumulate.

constexpr int N = 50000;   // nodes
constexpr int E = 800000;  // edges per graph
constexpr int D = 128;     // feature dim (in == out)
constexpr int L = 4;       // graphs

// ---------------------------------------------------------------------------
// Scatter SpMM: y[row] += val * x[col], 32 lanes per edge, float4 per lane.
// grid = E/8 blocks of 256 (8 edges per block), exact division.
// ---------------------------------------------------------------------------
__global__ __launch_bounds__(256) void scatter_kernel(
    const float* __restrict__ x,
    const int* __restrict__ rows,
    const int* __restrict__ cols,
    const float* __restrict__ vals,
    float* __restrict__ y)
{
    int t = blockIdx.x * 256 + threadIdx.x;
    int e = t >> 5;        // edge index
    int lane = t & 31;     // 32 lanes cover 128 floats as float4

    int r = rows[e];
    int c = cols[e];
    float v = vals[e];

    float4 xv = reinterpret_cast<const float4*>(x)[(size_t)c * (D / 4) + lane];
    float* dst = y + (size_t)r * D + lane * 4;
    unsafeAtomicAdd(dst + 0, v * xv.x);
    unsafeAtomicAdd(dst + 1, v * xv.y);
    unsafeAtomicAdd(dst + 2, v * xv.z);
    unsafeAtomicAdd(dst + 3, v * xv.w);
}

// ---------------------------------------------------------------------------
// GEMM-accumulate: out[n][f] (+)= sum_d y[n][d] * (m * W[d][f])   (+ bias on l==0)
// Block = 256 threads (4 waves); 32 rows per block (8 per wave);
// lane covers cols (2*lane, 2*lane+1). K=128 processed in two 64-chunks,
// W chunk (64x128 f32 = 32KB) and y tile (32x64 f32 = 8KB) staged in LDS.
// ---------------------------------------------------------------------------
__global__ __launch_bounds__(256) void gemm_acc_kernel(
    const float* __restrict__ y,
    const float* __restrict__ W,     // [D][D] for this graph
    const float* __restrict__ mix,   // &mixing_weight[l]
    const float* __restrict__ bias,
    float* __restrict__ out,
    int init)
{
    __shared__ float lds_w[64 * D];   // 32 KB
    __shared__ float lds_y[32][64];   // 8 KB

    const int tid = threadIdx.x;
    const int lane = tid & 63;
    const int wave = tid >> 6;
    const int r0 = blockIdx.x * 32;
    const int f0 = 2 * lane;
    const float m = mix[0];

    const int wr = r0 + wave * 8;

    float2 acc[8];
#pragma unroll
    for (int r = 0; r < 8; ++r) {
        int row = wr + r;
        if (init) {
            acc[r].x = bias[f0];
            acc[r].y = bias[f0 + 1];
        } else if (row < N) {
            acc[r] = *reinterpret_cast<const float2*>(out + (size_t)row * D + f0);
        } else {
            acc[r] = make_float2(0.f, 0.f);
        }
    }

    for (int kc = 0; kc < 2; ++kc) {
        // stage W chunk [64][128], scaled by m (coalesced float4 copy)
        {
            const float4* wsrc = reinterpret_cast<const float4*>(W + kc * 64 * D);
            float4* wdst = reinterpret_cast<float4*>(lds_w);
#pragma unroll
            for (int i = 0; i < 8; ++i) {
                int idx = i * 256 + tid;
                float4 wv = wsrc[idx];
                wdst[idx] = make_float4(m * wv.x, m * wv.y, m * wv.z, m * wv.w);
            }
        }
        // stage y tile [32 rows][64 d] (8 threads per row, 2 float4 each)
        {
            int rl = tid >> 3;
            int off = (tid & 7) * 8;
            int row = r0 + rl;
            float4 a = make_float4(0.f, 0.f, 0.f, 0.f), b = a;
            if (row < N) {
                const float4* src =
                    reinterpret_cast<const float4*>(y + (size_t)row * D + kc * 64 + off);
                a = src[0];
                b = src[1];
            }
            *reinterpret_cast<float4*>(&lds_y[rl][off]) = a;
            *reinterpret_cast<float4*>(&lds_y[rl][off + 4]) = b;
        }
        __syncthreads();

        const int wrow = wave * 8;
#pragma unroll
        for (int d4 = 0; d4 < 64; d4 += 4) {
            float4 yv[8];
#pragma unroll
            for (int r = 0; r < 8; ++r)
                yv[r] = *reinterpret_cast<const float4*>(&lds_y[wrow + r][d4]);
#pragma unroll
            for (int j = 0; j < 4; ++j) {
                float2 wv = *reinterpret_cast<const float2*>(&lds_w[(d4 + j) * D + f0]);
#pragma unroll
                for (int r = 0; r < 8; ++r) {
                    float ys = (j == 0) ? yv[r].x
                             : (j == 1) ? yv[r].y
                             : (j == 2) ? yv[r].z
                                        : yv[r].w;
                    acc[r].x = fmaf(ys, wv.x, acc[r].x);
                    acc[r].y = fmaf(ys, wv.y, acc[r].y);
                }
            }
        }
        __syncthreads();
    }

#pragma unroll
    for (int r = 0; r < 8; ++r) {
        int row = wr + r;
        if (row < N)
            *reinterpret_cast<float2*>(out + (size_t)row * D + f0) = acc[r];
    }
}

extern "C" void kernel_launch(void* const* d_in, const int* in_sizes, int n_in,
                              void* d_out, int out_size, void* d_ws, size_t ws_size,
                              hipStream_t stream)
{
    const float* x         = (const float*)d_in[0];
    const int*   edge_rows = (const int*)d_in[1];
    const int*   edge_cols = (const int*)d_in[2];
    const float* edge_vals = (const float*)d_in[3];
    const float* W         = (const float*)d_in[4];
    const float* mix       = (const float*)d_in[5];
    const float* bias      = (const float*)d_in[6];
    float* out = (float*)d_out;
    float* y   = (float*)d_ws;  // [N][D] f32, reused per graph (25.6 MB)

    const size_t ybytes = (size_t)N * D * sizeof(float);

    for (int l = 0; l < L; ++l) {
        hipMemsetAsync(y, 0, ybytes, stream);
        scatter_kernel<<<E / 8, 256, 0, stream>>>(
            x,
            edge_rows + (size_t)l * E,
            edge_cols + (size_t)l * E,
            edge_vals + (size_t)l * E,
            y);
        gemm_acc_kernel<<<(N + 31) / 32, 256, 0, stream>>>(
            y, W + (size_t)l * D * D, mix + l, bias, out, l == 0 ? 1 : 0);
    }
}

// Round 2
// 920.773 us; speedup vs baseline: 6.0084x; 6.0084x over previous
//
#include <hip/hip_runtime.h>

// AdaptiveGraphConvolution on MI355X (gfx950)
// out = sum_l m_l * (A_l @ x) @ W_l + bias
//
// R2: replace atomic-scatter SpMM (1.6 GB HBM write-through per graph, 1343 us)
// with on-device CSR build (counting sort) + gather SpMM (register accumulate,
// one coalesced row write). Workspace need: ~33.6 MB.

constexpr int N = 50000;   // nodes
constexpr int E = 800000;  // edges per graph
constexpr int D = 128;     // feature dim (in == out)
constexpr int L = 4;       // graphs

// ---------------------------------------------------------------------------
// 1) Histogram of row indices, all graphs in one launch. counts[g][N].
//    grid = (E/256, L)
// ---------------------------------------------------------------------------
__global__ __launch_bounds__(256) void hist_kernel(
    const int* __restrict__ edge_rows,   // [L][E]
    int* __restrict__ counts)            // [L][N]
{
    int e = blockIdx.x * 256 + threadIdx.x;
    int g = blockIdx.y;
    int r = edge_rows[(size_t)g * E + e];
    atomicAdd(&counts[(size_t)g * N + r], 1);
}

// ---------------------------------------------------------------------------
// 2) Per-graph exclusive scan counts -> row_ptr[N+1]; also resets counts[g]
//    to the start offsets (used as fill cursors). grid = L blocks of 1024.
// ---------------------------------------------------------------------------
__global__ __launch_bounds__(1024) void scan_kernel(
    int* __restrict__ counts,    // [L][N] in: histogram, out: cursor
    int* __restrict__ row_ptr)   // [L][N+1]
{
    __shared__ int sums[1024];
    const int g = blockIdx.x;
    int* cnt = counts + (size_t)g * N;
    int* rp  = row_ptr + (size_t)g * (N + 1);
    const int t = threadIdx.x;
    constexpr int CH = (N + 1023) / 1024;  // 49 elements per thread
    const int base = t * CH;

    int s = 0;
#pragma unroll 4
    for (int i = 0; i < CH; ++i) {
        int idx = base + i;
        if (idx < N) s += cnt[idx];
    }
    sums[t] = s;
    __syncthreads();
    // inclusive Hillis-Steele scan over 1024 partials
    for (int off = 1; off < 1024; off <<= 1) {
        int v = (t >= off) ? sums[t - off] : 0;
        __syncthreads();
        sums[t] += v;
        __syncthreads();
    }
    int pre = (t == 0) ? 0 : sums[t - 1];
    for (int i = 0; i < CH; ++i) {
        int idx = base + i;
        if (idx < N) {
            int c = cnt[idx];
            rp[idx] = pre;
            cnt[idx] = pre;   // cursor init for fill phase
            pre += c;
        }
    }
    if (t == 0) rp[N] = sums[1023];  // == E
}

// ---------------------------------------------------------------------------
// 3) Bin edges into CSR order: pairs[pos] = {col, val_bits}. grid = E/256.
// ---------------------------------------------------------------------------
__global__ __launch_bounds__(256) void fill_kernel(
    const int* __restrict__ rows,
    const int* __restrict__ cols,
    const float* __restrict__ vals,
    int* __restrict__ cursor,     // counts[g], start offsets
    int2* __restrict__ pairs)     // [E]
{
    int e = blockIdx.x * 256 + threadIdx.x;
    int r = rows[e];
    int pos = atomicAdd(&cursor[r], 1);
    pairs[pos] = make_int2(cols[e], __float_as_int(vals[e]));
}

// ---------------------------------------------------------------------------
// 4) Gather SpMM: one wave64 per row; lane holds float2 of the 128-wide acc.
//    y[r] = sum_j val_j * x[col_j].  grid = N*64/256 = 12500 blocks.
// ---------------------------------------------------------------------------
__global__ __launch_bounds__(256) void gather_kernel(
    const float* __restrict__ x,
    const int* __restrict__ row_ptr,   // [N+1]
    const int2* __restrict__ pairs,    // [E]
    float* __restrict__ y)             // [N][D]
{
    int row  = (blockIdx.x * 256 + threadIdx.x) >> 6;
    int lane = threadIdx.x & 63;
    if (row >= N) return;

    int beg = row_ptr[row];
    int end = row_ptr[row + 1];
    const float2* xf2 = reinterpret_cast<const float2*>(x);

    float2 acc = make_float2(0.f, 0.f);
    for (int j = beg; j < end; ++j) {
        int2 p = pairs[j];                         // broadcast load (all lanes same addr)
        float v = __int_as_float(p.y);
        float2 xv = xf2[(size_t)p.x * 64 + lane];  // coalesced 512B row gather
        acc.x = fmaf(v, xv.x, acc.x);
        acc.y = fmaf(v, xv.y, acc.y);
    }
    reinterpret_cast<float2*>(y)[(size_t)row * 64 + lane] = acc;
}

// ---------------------------------------------------------------------------
// 5) GEMM-accumulate: out[n][f] (+)= sum_d y[n][d] * (m * W[d][f]) (+bias on l==0)
//    (unchanged from R1 -- not the bottleneck)
// ---------------------------------------------------------------------------
__global__ __launch_bounds__(256) void gemm_acc_kernel(
    const float* __restrict__ y,
    const float* __restrict__ W,
    const float* __restrict__ mix,
    const float* __restrict__ bias,
    float* __restrict__ out,
    int init)
{
    __shared__ float lds_w[64 * D];   // 32 KB
    __shared__ float lds_y[32][64];   // 8 KB

    const int tid = threadIdx.x;
    const int lane = tid & 63;
    const int wave = tid >> 6;
    const int r0 = blockIdx.x * 32;
    const int f0 = 2 * lane;
    const float m = mix[0];
    const int wr = r0 + wave * 8;

    float2 acc[8];
#pragma unroll
    for (int r = 0; r < 8; ++r) {
        int row = wr + r;
        if (init) {
            acc[r].x = bias[f0];
            acc[r].y = bias[f0 + 1];
        } else if (row < N) {
            acc[r] = *reinterpret_cast<const float2*>(out + (size_t)row * D + f0);
        } else {
            acc[r] = make_float2(0.f, 0.f);
        }
    }

    for (int kc = 0; kc < 2; ++kc) {
        {
            const float4* wsrc = reinterpret_cast<const float4*>(W + kc * 64 * D);
            float4* wdst = reinterpret_cast<float4*>(lds_w);
#pragma unroll
            for (int i = 0; i < 8; ++i) {
                int idx = i * 256 + tid;
                float4 wv = wsrc[idx];
                wdst[idx] = make_float4(m * wv.x, m * wv.y, m * wv.z, m * wv.w);
            }
        }
        {
            int rl = tid >> 3;
            int off = (tid & 7) * 8;
            int row = r0 + rl;
            float4 a = make_float4(0.f, 0.f, 0.f, 0.f), b = a;
            if (row < N) {
                const float4* src =
                    reinterpret_cast<const float4*>(y + (size_t)row * D + kc * 64 + off);
                a = src[0];
                b = src[1];
            }
            *reinterpret_cast<float4*>(&lds_y[rl][off]) = a;
            *reinterpret_cast<float4*>(&lds_y[rl][off + 4]) = b;
        }
        __syncthreads();

        const int wrow = wave * 8;
#pragma unroll
        for (int d4 = 0; d4 < 64; d4 += 4) {
            float4 yv[8];
#pragma unroll
            for (int r = 0; r < 8; ++r)
                yv[r] = *reinterpret_cast<const float4*>(&lds_y[wrow + r][d4]);
#pragma unroll
            for (int j = 0; j < 4; ++j) {
                float2 wv = *reinterpret_cast<const float2*>(&lds_w[(d4 + j) * D + f0]);
#pragma unroll
                for (int r = 0; r < 8; ++r) {
                    float ys = (j == 0) ? yv[r].x
                             : (j == 1) ? yv[r].y
                             : (j == 2) ? yv[r].z
                                        : yv[r].w;
                    acc[r].x = fmaf(ys, wv.x, acc[r].x);
                    acc[r].y = fmaf(ys, wv.y, acc[r].y);
                }
            }
        }
        __syncthreads();
    }

#pragma unroll
    for (int r = 0; r < 8; ++r) {
        int row = wr + r;
        if (row < N)
            *reinterpret_cast<float2*>(out + (size_t)row * D + f0) = acc[r];
    }
}

extern "C" void kernel_launch(void* const* d_in, const int* in_sizes, int n_in,
                              void* d_out, int out_size, void* d_ws, size_t ws_size,
                              hipStream_t stream)
{
    const float* x         = (const float*)d_in[0];
    const int*   edge_rows = (const int*)d_in[1];
    const int*   edge_cols = (const int*)d_in[2];
    const float* edge_vals = (const float*)d_in[3];
    const float* W         = (const float*)d_in[4];
    const float* mix       = (const float*)d_in[5];
    const float* bias      = (const float*)d_in[6];
    float* out = (float*)d_out;

    // Workspace layout (~33.6 MB total):
    //   y       : N*D floats               (25.6 MB)
    //   counts  : L*N ints (hist->cursor)  (0.8 MB)
    //   row_ptr : L*(N+1) ints             (0.8 MB)
    //   pairs   : E int2, reused per graph (6.4 MB)
    float* y      = (float*)d_ws;
    int* counts   = (int*)(y + (size_t)N * D);
    int* row_ptr  = counts + (size_t)L * N;
    int2* pairs   = (int2*)(row_ptr + (size_t)L * (N + 1));

    hipMemsetAsync(counts, 0, (size_t)L * N * sizeof(int), stream);
    hist_kernel<<<dim3(E / 256, L), 256, 0, stream>>>(edge_rows, counts);
    scan_kernel<<<L, 1024, 0, stream>>>(counts, row_ptr);

    for (int l = 0; l < L; ++l) {
        fill_kernel<<<E / 256, 256, 0, stream>>>(
            edge_rows + (size_t)l * E,
            edge_cols + (size_t)l * E,
            edge_vals + (size_t)l * E,
            counts + (size_t)l * N,
            pairs);
        gather_kernel<<<(N * 64) / 256, 256, 0, stream>>>(
            x, row_ptr + (size_t)l * (N + 1), pairs, y);
        gemm_acc_kernel<<<(N + 31) / 32, 256, 0, stream>>>(
            y, W + (size_t)l * D * D, mix + l, bias, out, l == 0 ? 1 : 0);
    }
}